// Round 13
// baseline (1201.387 us; speedup 1.0000x reference)
//
#include <hip/hip_runtime.h>
#include <cstdint>
#include <cstddef>

// ---- problem constants ----
constexpr float DN = 0.35355339059327373f;   // 64^-0.25
constexpr float RATIO = 0.0625f;             // 256^-0.5
constexpr float EPSF = 1e-4f;

typedef __attribute__((ext_vector_type(8))) short short8;   // 16-bit MFMA fragment
typedef __attribute__((ext_vector_type(8))) _Float16 half8;
typedef __attribute__((ext_vector_type(4))) float f32x4;    // MFMA accumulator

// ---- workspace layout (byte offsets); proven budget >= 209,715,200 B ----
constexpr size_t OFF_H     = 0;              // fp32 residual 33,554,432
constexpr size_t OFF_YS    = 33554432;       // ysh fp16 (osh alias) 16,777,216
constexpr size_t OFF_WTS   = 50331648;       // all-layer fp16 weights 8,388,608 (+spare)
constexpr size_t OFF_QK    = 67108864;       // khi 16,777,216 | qhi 16,777,216 (fp16)
constexpr size_t OFF_BIG   = 100663296;      // kpT / ffb / x-split 67,108,864
constexpr size_t OFF_VT    = 167772160;      // vT [32][80][4096] fp16 20,971,520
constexpr size_t OFF_CTXP  = 188743680;      // ctx partials [4][32][256][80] f32 10,485,760
constexpr size_t OFF_CTXTH = 199229440;      // ctxT fp16 [32][80][256] 1,310,720
constexpr size_t OFF_DIAGQ = 201850880;      // 524,288
constexpr size_t OFF_DIAGK = 202375168;      // 524,288
constexpr size_t OFF_GMAX  = 203423744;      // 256 (4 per-layer slots used)
constexpr size_t OFF_POOL  = 203424000;      // 131,072
constexpr size_t OFF_PMTH  = 207749376;      // pm fp16 32,768
constexpr size_t OFF_PWTH  = 207814912;
constexpr size_t OFF_PWTL  = 207847680;
constexpr size_t WS_BYTES  = 207880448;

// per-layer short-offsets inside the fp16 WTS region (layer stride 1,048,576 shorts)
constexpr size_t WQF = 0;
constexpr size_t WKF = 65536;
constexpr size_t WVF = 131072;
constexpr size_t WOF = 196608;
constexpr size_t W1F = 262144;     // 524,288 shorts ([2048][256])
constexpr size_t W2F = 786432;     // 262,144 shorts ([256][1024])

__device__ __forceinline__ unsigned fkey(float f) {
    unsigned u = __float_as_uint(f);
    return (u & 0x80000000u) ? ~u : (u | 0x80000000u);
}
__device__ __forceinline__ float funkey(unsigned k) {
    unsigned u = (k & 0x80000000u) ? (k ^ 0x80000000u) : ~k;
    return __uint_as_float(u);
}
// Abramowitz-Stegun 7.1.26 rational erf, |err| <= 1.5e-7
__device__ __forceinline__ float erf_fast(float x) {
    float ax = fabsf(x);
    float t = 1.0f / fmaf(0.3275911f, ax, 1.0f);
    float p = t * fmaf(t, fmaf(t, fmaf(t, fmaf(t, 1.061405429f, -1.453152027f),
                                      1.421413741f), -0.284496736f), 0.254829592f);
    float r = 1.0f - p * __expf(-ax * ax);
    return copysignf(r, x);
}
__device__ __forceinline__ float gelu_fast(float x) {
    return 0.5f * x * (1.0f + erf_fast(x * 0.70710678118654752f));
}
__device__ __forceinline__ void splitf(float x, unsigned short& h, unsigned short& l) {
    unsigned u = __float_as_uint(x);
    unsigned hv = (u + 0x7FFFu + ((u >> 16) & 1)) >> 16;
    h = (unsigned short)hv;
    float lo = x - __uint_as_float(hv << 16);
    unsigned u2 = __float_as_uint(lo);
    l = (unsigned short)((u2 + 0x7FFFu + ((u2 >> 16) & 1)) >> 16);
}
__device__ __forceinline__ unsigned short bf16rne(float x) {
    unsigned u = __float_as_uint(x);
    return (unsigned short)((u + 0x7FFFu + ((u >> 16) & 1)) >> 16);
}
__device__ __forceinline__ unsigned short fp16rne(float x) {
    return __builtin_bit_cast(unsigned short, (_Float16)x);
}
template<bool F16>
__device__ __forceinline__ f32x4 mfma16(short8 a, short8 b, f32x4 c) {
    if constexpr (F16)
        return __builtin_amdgcn_mfma_f32_16x16x32_f16(
            __builtin_bit_cast(half8, a), __builtin_bit_cast(half8, b), c, 0, 0, 0);
    else
        return __builtin_amdgcn_mfma_f32_16x16x32_bf16(a, b, c, 0, 0, 0);
}
// XCD-aware block swizzle (requires total blocks % 8 == 0)
__device__ __forceinline__ void xcd_swz(int& bx, int& by) {
    const int gx = gridDim.x;
    const int total = gx * gridDim.y;
    int flat = blockIdx.y * gx + blockIdx.x;
    flat = (flat & 7) * (total >> 3) + (flat >> 3);
    bx = flat % gx; by = flat / gx;
}

// ---- async global->LDS 16B (wave-uniform base + lane*16, linear dest) ----
#if defined(__has_builtin)
#if __has_builtin(__builtin_amdgcn_global_load_lds)
#define HAVE_GLDS 1
#endif
#endif
__device__ __forceinline__ void glds16(const unsigned short* g, unsigned short* l) {
#ifdef HAVE_GLDS
    __builtin_amdgcn_global_load_lds(
        (const __attribute__((address_space(1))) unsigned int*)g,
        (__attribute__((address_space(3))) unsigned int*)l, 16, 0, 0);
#else
    *(uint4*)l = *(const uint4*)g;
#endif
}

__global__ void fill_sentinel(float* out, int n) {
    int i = threadIdx.x;
    if (i < n) out[i] = 12345.0f;
}
// fill vT rows 64..79 (row 64 = 1.0 fp16 for ksum fold) + zero per-layer gmax keys
__global__ __launch_bounds__(256) void vt_init(unsigned short* __restrict__ vT, unsigned* __restrict__ gm) {
    int i = blockIdx.x * 256 + threadIdx.x;        // 262,144 uint4
    if (i < 4) gm[i] = 0u;
    const int bh = i >> 13;
    const int r = (i >> 9) & 15;
    const unsigned val = (r == 0) ? 0x3C003C00u : 0u;
    uint4 q; q.x = val; q.y = val; q.z = val; q.w = val;
    *(uint4*)(vT + ((size_t)bh * 80 + 64 + r) * 4096 + ((size_t)(i & 511) << 3)) = q;
}

// ---- elementwise split (optional scale) ----
__global__ __launch_bounds__(256) void split_scale(
    const float* __restrict__ src, unsigned short* __restrict__ hi,
    unsigned short* __restrict__ lo, int n, float scale)
{
    int i = blockIdx.x * 256 + threadIdx.x;
    if (i < n) {
        unsigned short h, l;
        splitf(src[i] * scale, h, l);
        hi[i] = h; lo[i] = l;
    }
}

// ---- fp32 -> fp16 with scale ----
__global__ __launch_bounds__(256) void tofp16_scale(
    const float* __restrict__ src, unsigned short* __restrict__ dst, int n, float scale)
{
    int i = blockIdx.x * 256 + threadIdx.x;
    if (i < n) dst[i] = fp16rne(src[i] * scale);
}

// ---- transpose-split weights: W [K,N] fp32 -> Wt hi/lo [N,K] bf16 (proj only) ----
__global__ __launch_bounds__(256) void splitT(
    const float* __restrict__ W, unsigned short* __restrict__ hi,
    unsigned short* __restrict__ lo, int kshift, int N)
{
    int i = blockIdx.x * 256 + threadIdx.x;
    int K = 1 << kshift;
    int n = i >> kshift, k = i & (K - 1);
    unsigned short h, l;
    splitf(W[(size_t)k * N + n], h, l);
    hi[i] = h; lo[i] = l;
}

// ---- all-layer weight transpose -> fp16 [N][K]; one dispatch, 4,194,304 elems ----
__global__ __launch_bounds__(256) void split_weights(
    const float* __restrict__ wq, const float* __restrict__ wk,
    const float* __restrict__ wv, const float* __restrict__ wo,
    const float* __restrict__ w1, const float* __restrict__ w2,
    unsigned short* __restrict__ dst)
{
    const int i = blockIdx.x * 256 + threadIdx.x;
    const int lay = i >> 20;
    const int r = i & 1048575;
    float val; size_t oh;
    if (r < 262144) {
        const int m = r >> 16, e = r & 65535;
        const int n = e >> 8, k = e & 255;
        const float* W = (m == 0 ? wq : m == 1 ? wk : m == 2 ? wv : wo);
        val = W[(size_t)lay * 65536 + k * 256 + n];
        oh = (size_t)lay * 1048576 + (size_t)m * 65536 + e;
    } else if (r < 786432) {
        const int e = r - 262144;
        const int n = e >> 8, k = e & 255;
        val = w1[(size_t)lay * 524288 + (size_t)k * 2048 + n];
        oh = (size_t)lay * 1048576 + W1F + e;
    } else {
        const int e = r - 786432;
        const int n = e >> 10, k = e & 1023;
        val = w2[(size_t)lay * 262144 + (size_t)k * 256 + n];
        oh = (size_t)lay * 1048576 + W2F + e;
    }
    dst[oh] = fp16rne(val);
}

// ---- LayerNorm -> single fp16 plane (layer-0 only) ----
__global__ __launch_bounds__(256) void ln_f16(
    const float* __restrict__ x, const float* __restrict__ g,
    const float* __restrict__ b, unsigned short* __restrict__ yhi)
{
    const int row = blockIdx.x * 4 + (threadIdx.x >> 6);
    const int lane = threadIdx.x & 63;
    float4 t = *(const float4*)&x[(size_t)row * 256 + lane * 4];
    float s = t.x + t.y + t.z + t.w;
#pragma unroll
    for (int sh = 1; sh < 64; sh <<= 1) s += __shfl_xor(s, sh);
    const float mu = s * (1.0f / 256.0f);
    const float dx = t.x - mu, dy = t.y - mu, dz = t.z - mu, dw = t.w - mu;
    float vv = dx * dx + dy * dy + dz * dz + dw * dw;
#pragma unroll
    for (int sh = 1; sh < 64; sh <<= 1) vv += __shfl_xor(vv, sh);
    const float rstd = rsqrtf(vv * (1.0f / 256.0f) + 1e-5f);
    float4 gv = *(const float4*)&g[lane * 4];
    float4 bv = *(const float4*)&b[lane * 4];
    unsigned short h0 = fp16rne(dx * rstd * gv.x + bv.x);
    unsigned short h1 = fp16rne(dy * rstd * gv.y + bv.y);
    unsigned short h2 = fp16rne(dz * rstd * gv.z + bv.z);
    unsigned short h3 = fp16rne(dw * rstd * gv.w + bv.w);
    uint2 ph;
    ph.x = (unsigned)h0 | ((unsigned)h1 << 16); ph.y = (unsigned)h2 | ((unsigned)h3 << 16);
    *(uint2*)&yhi[(size_t)row * 256 + lane * 4] = ph;
}

// ---- bf16/f16 MFMA GEMM, tile 128x128, BK=64, 4 waves ----
// EPI: 0 bias->f32 C | 4 global max -> keys[0]
//      6 kp = exp epilogue fp16 + TRANSPOSED write to kpT[bh][m][n]
template<int EPI, bool ASPLIT, bool BSPLIT, bool F16>
__global__ __launch_bounds__(256) void gemm_mf(
    const unsigned short* __restrict__ Ahi, const unsigned short* __restrict__ Alo, int lda,
    const unsigned short* __restrict__ Bhi, const unsigned short* __restrict__ Blo, int ldb,
    int K,
    const float* __restrict__ bias, const float* __restrict__ res,
    float* __restrict__ C, int ldc,
    unsigned short* __restrict__ Obf,
    const float* __restrict__ diag, unsigned* __restrict__ keys)
{
    constexpr int NP = (ASPLIT ? 2 : 1) + (BSPLIT ? 2 : 1);
    constexpr int PB = ASPLIT ? 2 : 1;                 // B-hi plane index
    constexpr int NEED = (EPI == 6) ? 16384 : 0;
    constexpr int LDSN = (NP * 8192 > NEED) ? NP * 8192 : NEED;
    __shared__ unsigned short lds[LDSN];
    __shared__ float red[4];
#define LX(p, h, r, c) lds[(p) * 8192 + (h) * 4096 + (r) * 32 + (c)]
    int bx, by; xcd_swz(bx, by);
    const int tid = threadIdx.x;
    const int m0 = by * 128, n0 = bx * 128;
    const int sr = tid >> 2, sc = (tid & 3) * 8;
    const unsigned short* ga_h = Ahi + (size_t)(m0 + sr) * lda + sc;
    const unsigned short* ga_l = ASPLIT ? (Alo + (size_t)(m0 + sr) * lda + sc) : nullptr;
    const unsigned short* gb_h = Bhi + (size_t)(n0 + sr) * ldb + sc;
    const unsigned short* gb_l = BSPLIT ? (Blo + (size_t)(n0 + sr) * ldb + sc) : nullptr;
    unsigned short* lp = lds + tid * 8;
    const int l = tid & 63, w = tid >> 6;
    const int wr = (w >> 1) * 64, wc = (w & 1) * 64;
    const int fr = l & 15, fq = l >> 4;

    f32x4 acc[4][4];
#pragma unroll
    for (int i = 0; i < 4; ++i)
#pragma unroll
        for (int j = 0; j < 4; ++j) acc[i][j] = (f32x4){0.f, 0.f, 0.f, 0.f};

    for (int k0 = 0; k0 < K; k0 += 64) {
        glds16(ga_h + k0, lp);
        glds16(ga_h + (size_t)64 * lda + k0, lp + 2048);
        glds16(ga_h + k0 + 32, lp + 4096);
        glds16(ga_h + (size_t)64 * lda + k0 + 32, lp + 6144);
        if (ASPLIT) {
            glds16(ga_l + k0, lp + 8192);
            glds16(ga_l + (size_t)64 * lda + k0, lp + 10240);
            glds16(ga_l + k0 + 32, lp + 12288);
            glds16(ga_l + (size_t)64 * lda + k0 + 32, lp + 14336);
        }
        glds16(gb_h + k0, lp + PB * 8192);
        glds16(gb_h + (size_t)64 * ldb + k0, lp + PB * 8192 + 2048);
        glds16(gb_h + k0 + 32, lp + PB * 8192 + 4096);
        glds16(gb_h + (size_t)64 * ldb + k0 + 32, lp + PB * 8192 + 6144);
        if (BSPLIT) {
            glds16(gb_l + k0, lp + (PB + 1) * 8192);
            glds16(gb_l + (size_t)64 * ldb + k0, lp + (PB + 1) * 8192 + 2048);
            glds16(gb_l + k0 + 32, lp + (PB + 1) * 8192 + 4096);
            glds16(gb_l + (size_t)64 * ldb + k0 + 32, lp + (PB + 1) * 8192 + 6144);
        }
        __syncthreads();
#pragma unroll
        for (int h2 = 0; h2 < 2; ++h2) {
            short8 ah[4], al[4];
#pragma unroll
            for (int mf = 0; mf < 4; ++mf) {
                ah[mf] = *(const short8*)&LX(0, h2, wr + mf * 16 + fr, fq * 8);
                if (ASPLIT) al[mf] = *(const short8*)&LX(1, h2, wr + mf * 16 + fr, fq * 8);
            }
#pragma unroll
            for (int nf = 0; nf < 4; ++nf) {
                short8 bh = *(const short8*)&LX(PB, h2, wc + nf * 16 + fr, fq * 8);
#pragma unroll
                for (int mf = 0; mf < 4; ++mf) {
                    acc[mf][nf] = mfma16<F16>(ah[mf], bh, acc[mf][nf]);
                    if (ASPLIT) acc[mf][nf] = mfma16<F16>(al[mf], bh, acc[mf][nf]);
                }
                if (BSPLIT) {
                    short8 bl = *(const short8*)&LX(PB + 1, h2, wc + nf * 16 + fr, fq * 8);
#pragma unroll
                    for (int mf = 0; mf < 4; ++mf)
                        acc[mf][nf] = mfma16<F16>(ah[mf], bl, acc[mf][nf]);
                }
            }
        }
        __syncthreads();
    }

    if constexpr (EPI == 4) {
        float m = -3.4e38f;
#pragma unroll
        for (int mf = 0; mf < 4; ++mf)
#pragma unroll
            for (int nf = 0; nf < 4; ++nf)
#pragma unroll
                for (int v = 0; v < 4; ++v) m = fmaxf(m, acc[mf][nf][v]);
#pragma unroll
        for (int s = 1; s < 64; s <<= 1) m = fmaxf(m, __shfl_xor(m, s));
        if (l == 0) red[w] = m;
        __syncthreads();
        if (tid == 0)
            atomicMax(keys, fkey(fmaxf(fmaxf(red[0], red[1]), fmaxf(red[2], red[3]))));
    } else if constexpr (EPI == 6) {
        const float Mg = funkey(*keys);
        unsigned short* tb = lds;
#pragma unroll
        for (int mf = 0; mf < 4; ++mf)
#pragma unroll
            for (int v = 0; v < 4; ++v) {
                const int rl = wr + mf * 16 + fq * 4 + v;
                const float dg = diag[m0 + rl] + Mg;
#pragma unroll
                for (int nf = 0; nf < 4; ++nf) {
                    const int cl = wc + nf * 16 + fr;
                    tb[rl * 128 + cl] = fp16rne(RATIO * (__expf(acc[mf][nf][v] - dg) + EPSF));
                }
            }
        __syncthreads();
        const int tokbase = m0 >> 2;
        const int b = tokbase >> 12, nib = tokbase & 4095;
        const int ml = tid & 127, g2 = tid >> 7;
#pragma unroll
        for (int hh2 = 0; hh2 < 2; ++hh2) {
            const int hh = g2 * 2 + hh2;
            unsigned short* dst = Obf + ((size_t)((b * 4 + hh) * 256 + n0 + ml)) * 4096 + nib;
#pragma unroll
            for (int qq = 0; qq < 4; ++qq) {
                uint4 qv;
                unsigned wv[4];
#pragma unroll
                for (int j = 0; j < 4; ++j) {
                    unsigned s0 = tb[((qq * 8 + j * 2 + 0) * 4 + hh) * 128 + ml];
                    unsigned s1 = tb[((qq * 8 + j * 2 + 1) * 4 + hh) * 128 + ml];
                    wv[j] = s0 | (s1 << 16);
                }
                qv.x = wv[0]; qv.y = wv[1]; qv.z = wv[2]; qv.w = wv[3];
                *(uint4*)(dst + qq * 8) = qv;
            }
        }
    } else {
#pragma unroll
        for (int nf = 0; nf < 4; ++nf) {
            const int col = n0 + wc + nf * 16 + fr;
            float bb = 0.f;
            if (bias != nullptr) bb = bias[col];
#pragma unroll
            for (int mf = 0; mf < 4; ++mf) {
#pragma unroll
                for (int v = 0; v < 4; ++v) {
                    const int row = m0 + wr + mf * 16 + fq * 4 + v;
                    const size_t off = (size_t)row * ldc + col;
                    C[off] = acc[mf][nf][v] + bb;
                }
            }
        }
    }
#undef LX
}

// ---- weight GEMM (fp16) + residual + LayerNorm fused; 128x256 tile, 512 thr ----
// grid 256 blocks; writes h fp32 (acc+bias+res) and ysh fp16 (LN of h row).
__global__ __launch_bounds__(512) void gemm_w_ln(
    const unsigned short* __restrict__ A, int lda, int K,
    const unsigned short* __restrict__ W,
    const float* __restrict__ bias, float* __restrict__ h,
    const float* __restrict__ lng, const float* __restrict__ lnb,
    unsigned short* __restrict__ ysh)
{
    __shared__ unsigned short ldsA[8192];    // [2 halves][128][32]
    __shared__ unsigned short ldsB[16384];   // [2 halves][256][32]
    int flat = blockIdx.x;
    flat = (flat & 7) * ((int)gridDim.x >> 3) + (flat >> 3);
    const int m0 = flat * 128;
    const int tid = threadIdx.x;
    const int sr = tid >> 2, sc = (tid & 3) * 8;
    const unsigned short* ga = A + (size_t)(m0 + sr) * lda + sc;
    const unsigned short* gb = W + (size_t)sr * K + sc;
    unsigned short* lpA = ldsA + tid * 8;
    const int l = tid & 63, w = tid >> 6;
    const int wr = (w >> 2) * 64, wc = (w & 3) * 64;
    const int fr = l & 15, fq = l >> 4;

    f32x4 acc[4][4];
#pragma unroll
    for (int i = 0; i < 4; ++i)
#pragma unroll
        for (int j = 0; j < 4; ++j) acc[i][j] = (f32x4){0.f, 0.f, 0.f, 0.f};

    for (int k0 = 0; k0 < K; k0 += 64) {
        glds16(ga + k0, lpA);
        glds16(ga + k0 + 32, lpA + 4096);
        glds16(gb + k0, ldsB + tid * 8);
        glds16(gb + (size_t)128 * K + k0, ldsB + 4096 + tid * 8);
        glds16(gb + k0 + 32, ldsB + 8192 + tid * 8);
        glds16(gb + (size_t)128 * K + k0 + 32, ldsB + 12288 + tid * 8);
        __syncthreads();
#pragma unroll
        for (int h2 = 0; h2 < 2; ++h2) {
            short8 ah[4];
#pragma unroll
            for (int mf = 0; mf < 4; ++mf)
                ah[mf] = *(const short8*)&ldsA[h2 * 4096 + (wr + mf * 16 + fr) * 32 + fq * 8];
#pragma unroll
            for (int nf = 0; nf < 4; ++nf) {
                short8 bv = *(const short8*)&ldsB[h2 * 8192 + (wc + nf * 16 + fr) * 32 + fq * 8];
#pragma unroll
                for (int mf = 0; mf < 4; ++mf)
                    acc[mf][nf] = mfma16<true>(ah[mf], bv, acc[mf][nf]);
            }
        }
        __syncthreads();
    }

    float* red = (float*)ldsA;   // red1 [128][4] at [0..512); red2 at [512..1024)
    // pass 1: val = acc + bias + res; write h; row-sum
#pragma unroll
    for (int mf = 0; mf < 4; ++mf)
#pragma unroll
        for (int v = 0; v < 4; ++v) {
            float s = 0.f;
#pragma unroll
            for (int nf = 0; nf < 4; ++nf) {
                const int col = wc + nf * 16 + fr;
                const int row = m0 + wr + mf * 16 + fq * 4 + v;
                const size_t off = (size_t)row * 256 + col;
                float val = acc[mf][nf][v] + bias[col] + h[off];
                h[off] = val;
                acc[mf][nf][v] = val;
                s += val;
            }
            s += __shfl_xor(s, 1); s += __shfl_xor(s, 2);
            s += __shfl_xor(s, 4); s += __shfl_xor(s, 8);
            if (fr == 0) red[(wr + mf * 16 + fq * 4 + v) * 4 + (w & 3)] = s;
        }
    __syncthreads();
    float mu[4][4];
#pragma unroll
    for (int mf = 0; mf < 4; ++mf)
#pragma unroll
        for (int v = 0; v < 4; ++v) {
            const int rl = wr + mf * 16 + fq * 4 + v;
            mu[mf][v] = (red[rl * 4] + red[rl * 4 + 1] + red[rl * 4 + 2] + red[rl * 4 + 3])
                        * (1.0f / 256.0f);
        }
    // pass 2: variance (exact (x-mu)^2 form)
#pragma unroll
    for (int mf = 0; mf < 4; ++mf)
#pragma unroll
        for (int v = 0; v < 4; ++v) {
            float s = 0.f;
#pragma unroll
            for (int nf = 0; nf < 4; ++nf) {
                const float d = acc[mf][nf][v] - mu[mf][v];
                s += d * d;
            }
            s += __shfl_xor(s, 1); s += __shfl_xor(s, 2);
            s += __shfl_xor(s, 4); s += __shfl_xor(s, 8);
            if (fr == 0) red[512 + (wr + mf * 16 + fq * 4 + v) * 4 + (w & 3)] = s;
        }
    __syncthreads();
#pragma unroll
    for (int mf = 0; mf < 4; ++mf)
#pragma unroll
        for (int v = 0; v < 4; ++v) {
            const int rl = wr + mf * 16 + fq * 4 + v;
            const float var = (red[512 + rl * 4] + red[512 + rl * 4 + 1] +
                               red[512 + rl * 4 + 2] + red[512 + rl * 4 + 3]) * (1.0f / 256.0f);
            const float rstd = rsqrtf(var + 1e-5f);
            const float m_ = mu[mf][v];
#pragma unroll
            for (int nf = 0; nf < 4; ++nf) {
                const int col = wc + nf * 16 + fr;
                ysh[(size_t)(m0 + rl) * 256 + col] =
                    fp16rne((acc[mf][nf][v] - m_) * rstd * lng[col] + lnb[col]);
            }
        }
}

// ---- merged QKV GEMM (fp16 A & W, 1 MFMA/site); grid (2, 768) ----
__global__ __launch_bounds__(256) void gemm_qkv(
    const unsigned short* __restrict__ A, const unsigned short* __restrict__ wl,
    const float* __restrict__ bq, const float* __restrict__ bk, const float* __restrict__ bv,
    unsigned short* __restrict__ vT, unsigned short* __restrict__ khi,
    unsigned short* __restrict__ qhi, float* __restrict__ diagq, float* __restrict__ diagk)
{
    __shared__ unsigned short lds[16384];
    int bx, by; xcd_swz(bx, by);
    const int sel = by >> 8;
    const int m0 = (by & 255) * 128, n0 = bx * 128;
    const unsigned short* Bw = wl + (sel == 0 ? WVF : sel == 1 ? WKF : WQF);
    const float* bias = (sel == 0 ? bv : sel == 1 ? bk : bq);
    const int tid = threadIdx.x;
    const int sr = tid >> 2, sc = (tid & 3) * 8;
    const unsigned short* ga = A + (size_t)(m0 + sr) * 256 + sc;
    const unsigned short* gb = Bw + (size_t)(n0 + sr) * 256 + sc;
    unsigned short* lp = lds + tid * 8;
    const int l = tid & 63, w = tid >> 6;
    const int wr = (w >> 1) * 64, wc = (w & 1) * 64;
    const int fr = l & 15, fq = l >> 4;

    f32x4 acc[4][4];
#pragma unroll
    for (int i = 0; i < 4; ++i)
#pragma unroll
        for (int j = 0; j < 4; ++j) acc[i][j] = (f32x4){0.f, 0.f, 0.f, 0.f};

    for (int k0 = 0; k0 < 256; k0 += 64) {
        glds16(ga + k0, lp);
        glds16(ga + (size_t)64 * 256 + k0, lp + 2048);
        glds16(ga + k0 + 32, lp + 4096);
        glds16(ga + (size_t)64 * 256 + k0 + 32, lp + 6144);
        glds16(gb + k0, lp + 8192);
        glds16(gb + (size_t)64 * 256 + k0, lp + 10240);
        glds16(gb + k0 + 32, lp + 12288);
        glds16(gb + (size_t)64 * 256 + k0 + 32, lp + 14336);
        __syncthreads();
#pragma unroll
        for (int h2 = 0; h2 < 2; ++h2) {
            short8 ah[4];
#pragma unroll
            for (int mf = 0; mf < 4; ++mf)
                ah[mf] = *(const short8*)&lds[h2 * 4096 + (wr + mf * 16 + fr) * 32 + fq * 8];
#pragma unroll
            for (int nf = 0; nf < 4; ++nf) {
                short8 bh = *(const short8*)&lds[8192 + h2 * 4096 + (wc + nf * 16 + fr) * 32 + fq * 8];
#pragma unroll
                for (int mf = 0; mf < 4; ++mf)
                    acc[mf][nf] = mfma16<true>(ah[mf], bh, acc[mf][nf]);
            }
        }
        __syncthreads();
    }

    if (sel == 0) {
        unsigned short* tb = lds;
#pragma unroll
        for (int mf = 0; mf < 4; ++mf)
#pragma unroll
            for (int nf = 0; nf < 4; ++nf) {
                const int cl = wc + nf * 16 + fr;
                const float bb = bias[n0 + cl];
#pragma unroll
                for (int v = 0; v < 4; ++v) {
                    const int rl = wr + mf * 16 + fq * 4 + v;
                    tb[rl * 128 + cl] = fp16rne(acc[mf][nf][v] + bb);
                }
            }
        __syncthreads();
        const int b = m0 >> 12, nib = m0 & 4095;
        const int cl = tid & 127, half = tid >> 7;
        const int ch = n0 + cl, hh = ch >> 6, d = ch & 63;
        unsigned short* dst = vT + ((size_t)((b * 4 + hh) * 80 + d)) * 4096 + nib + half * 64;
#pragma unroll
        for (int qq = 0; qq < 8; ++qq) {
            uint4 qv;
            unsigned wv[4];
#pragma unroll
            for (int j = 0; j < 4; ++j) {
                unsigned s0 = tb[(half * 64 + qq * 8 + j * 2 + 0) * 128 + cl];
                unsigned s1 = tb[(half * 64 + qq * 8 + j * 2 + 1) * 128 + cl];
                wv[j] = s0 | (s1 << 16);
            }
            qv.x = wv[0]; qv.y = wv[1]; qv.z = wv[2]; qv.w = wv[3];
            *(uint4*)(dst + qq * 8) = qv;
        }
    } else {
        float* diag = (sel == 1 ? diagk : diagq);
        unsigned short* Obf = (sel == 1 ? khi : qhi);
        const int head = (n0 + wc) >> 6;
#pragma unroll
        for (int mf = 0; mf < 4; ++mf) {
            float sq[4] = {0.f, 0.f, 0.f, 0.f};
#pragma unroll
            for (int nf = 0; nf < 4; ++nf) {
                const int col = n0 + wc + nf * 16 + fr;
                const float bb = bias[col];
#pragma unroll
                for (int v = 0; v < 4; ++v) {
                    const int row = m0 + wr + mf * 16 + fq * 4 + v;
                    float val = acc[mf][nf][v] + bb;
                    Obf[(size_t)row * 256 + col] = fp16rne(val);
                    sq[v] += val * val;
                }
            }
#pragma unroll
            for (int v = 0; v < 4; ++v) {
                float s = sq[v];
                s += __shfl_xor(s, 1); s += __shfl_xor(s, 2);
                s += __shfl_xor(s, 4); s += __shfl_xor(s, 8);
                if (fr == 0)
                    diag[(size_t)(m0 + wr + mf * 16 + fq * 4 + v) * 4 + head] = s * 0.0625f;
            }
        }
    }
}

// ---- fused GLU GEMM: A fp16, W fp16 single -> 2 MFMA/site; BK=64; fast gelu ----
__global__ __launch_bounds__(256) void gemm_glu(
    const unsigned short* __restrict__ Ahi, const unsigned short* __restrict__ Wf,
    const float* __restrict__ b1, unsigned short* __restrict__ Obf)
{
    __shared__ unsigned short ldsA[8192];      // [2 halves][128][32]
    __shared__ unsigned short ldsB[8192];      // 2 planes x [2 halves][64][32]
    int bx, by; xcd_swz(bx, by);
    const int tid = threadIdx.x;
    const int m0 = by * 128, p0 = bx * 64;
    const int sr = tid >> 2, sc = (tid & 3) * 8;
    const unsigned short* ga  = Ahi + (size_t)(m0 + sr) * 256 + sc;
    const unsigned short* gba = Wf + (size_t)(p0 + sr) * 256 + sc;
    const unsigned short* gbg = Wf + (size_t)(1024 + p0 + sr) * 256 + sc;
    unsigned short* lpA = ldsA + tid * 8;
    unsigned short* lpB = ldsB + tid * 8;
    const int l = tid & 63, w = tid >> 6;
    const int wr = (w >> 1) * 64, wc = (w & 1) * 32;
    const int fr = l & 15, fq = l >> 4;

    f32x4 aa[4][2], ag[4][2];
#pragma unroll
    for (int i = 0; i < 4; ++i)
#pragma unroll
        for (int j = 0; j < 2; ++j) {
            aa[i][j] = (f32x4){0.f, 0.f, 0.f, 0.f};
            ag[i][j] = (f32x4){0.f, 0.f, 0.f, 0.f};
        }

    for (int k0 = 0; k0 < 256; k0 += 64) {
        glds16(ga + k0, lpA);
        glds16(ga + 64 * 256 + k0, lpA + 2048);
        glds16(ga + k0 + 32, lpA + 4096);
        glds16(ga + 64 * 256 + k0 + 32, lpA + 6144);
        glds16(gba + k0, lpB);
        glds16(gba + k0 + 32, lpB + 2048);
        glds16(gbg + k0, lpB + 4096);
        glds16(gbg + k0 + 32, lpB + 6144);
        __syncthreads();
#pragma unroll
        for (int h2 = 0; h2 < 2; ++h2) {
            short8 ah[4];
#pragma unroll
            for (int mf = 0; mf < 4; ++mf)
                ah[mf] = *(const short8*)&ldsA[h2 * 4096 + (wr + mf * 16 + fr) * 32 + fq * 8];
#pragma unroll
            for (int nf = 0; nf < 2; ++nf) {
                const int br_ = h2 * 2048 + (wc + nf * 16 + fr) * 32 + fq * 8;
                short8 bva = *(const short8*)&ldsB[br_];
                short8 bvg = *(const short8*)&ldsB[4096 + br_];
#pragma unroll
                for (int mf = 0; mf < 4; ++mf) {
                    aa[mf][nf] = mfma16<true>(ah[mf], bva, aa[mf][nf]);
                    ag[mf][nf] = mfma16<true>(ah[mf], bvg, ag[mf][nf]);
                }
            }
        }
        __syncthreads();
    }
#pragma unroll
    for (int nf = 0; nf < 2; ++nf) {
        const int ch = p0 + wc + nf * 16 + fr;
        const float ba = b1[ch], bg = b1[1024 + ch];
#pragma unroll
        for (int mf = 0; mf < 4; ++mf) {
#pragma unroll
            for (int v = 0; v < 4; ++v) {
                const int row = m0 + wr + mf * 16 + fq * 4 + v;
                float u = aa[mf][nf][v] + ba, g = ag[mf][nf][v] + bg;
                Obf[(size_t)row * 1024 + ch] = fp16rne(gelu_fast(u) * g);
            }
        }
    }
}

// ---- ctx GEMM (fp16): 64-row x 80-col tile, K-chunk 1024, BK=64; grid (16,32) ----
__global__ __launch_bounds__(256) void ctx_mfma(
    const unsigned short* __restrict__ kpT, const unsigned short* __restrict__ vT,
    float* __restrict__ ctxp)
{
    __shared__ unsigned short la[4096];        // [2 halves][64][32]
    __shared__ unsigned short lb[5120];        // [2 halves][80][32]
    int bx, by; xcd_swz(bx, by);
    const int bh = by, mt = bx & 3, kc = bx >> 2;
    const int tid = threadIdx.x;
    const int l = tid & 63, w = tid >> 6;
    const int wr = w * 16, fr = l & 15, fq = l >> 4;
    const int sr = tid >> 2, sc = (tid & 3) * 8;
    const unsigned short* ga  = kpT + ((size_t)bh * 256 + mt * 64 + sr) * 4096 + kc * 1024 + sc;
    const unsigned short* gb  = vT + ((size_t)bh * 80 + sr) * 4096 + kc * 1024 + sc;
    const unsigned short* gb2 = vT + ((size_t)bh * 80 + 64 + sr) * 4096 + kc * 1024 + sc;

    f32x4 acc[5];
#pragma unroll
    for (int j = 0; j < 5; ++j) acc[j] = (f32x4){0.f, 0.f, 0.f, 0.f};

    for (int k0 = 0; k0 < 1024; k0 += 64) {
        glds16(ga + k0, la + tid * 8);
        glds16(ga + k0 + 32, la + 2048 + tid * 8);
        glds16(gb + k0, lb + tid * 8);
        glds16(gb + k0 + 32, lb + 2560 + tid * 8);
        if (tid < 64) {
            glds16(gb2 + k0, lb + 2048 + tid * 8);
            glds16(gb2 + k0 + 32, lb + 2560 + 2048 + tid * 8);
        }
        __syncthreads();
#pragma unroll
        for (int h2 = 0; h2 < 2; ++h2) {
            short8 av = *(const short8*)&la[h2 * 2048 + (wr + fr) * 32 + fq * 8];
#pragma unroll
            for (int nf = 0; nf < 5; ++nf) {
                short8 bv = *(const short8*)&lb[h2 * 2560 + (nf * 16 + fr) * 32 + fq * 8];
                acc[nf] = mfma16<true>(av, bv, acc[nf]);
            }
        }
        __syncthreads();
    }
#pragma unroll
    for (int v = 0; v < 4; ++v) {
        const int row = mt * 64 + wr + fq * 4 + v;
#pragma unroll
        for (int nf = 0; nf < 5; ++nf)
            ctxp[((size_t)(kc * 32 + bh) * 256 + row) * 80 + nf * 16 + fr] = acc[nf][v];
    }
}

// ---- reduce ctx partials over 4 k-chunks, transpose -> ctxT fp16 [bh][80][256] ----
__global__ __launch_bounds__(256) void ctx_fix(
    const float* __restrict__ ctxp, unsigned short* __restrict__ cth)
{
    __shared__ float s[64][81];
    const int m0 = blockIdx.x * 64, bh = blockIdx.y;
    const int tid = threadIdx.x;
    for (int i = tid; i < 5120; i += 256) {
        const int ml = i / 80, dc = i % 80;
        float sum = 0.f;
#pragma unroll
        for (int kc = 0; kc < 4; ++kc)
            sum += ctxp[((size_t)(kc * 32 + bh) * 256 + m0 + ml) * 80 + dc];
        s[ml][dc] = sum;
    }
    __syncthreads();
    for (int i = tid; i < 5120; i += 256) {
        const int dc = i >> 6, ml = i & 63;
        cth[((size_t)bh * 80 + dc) * 256 + m0 + ml] = fp16rne(s[ml][dc]);
    }
}

// ---- fused q-side (fp16), 64-token tiles; grid (64, 32) ----
__global__ __launch_bounds__(256) void qo_mfma(
    const unsigned short* __restrict__ qhi, const unsigned short* __restrict__ pmh,
    const unsigned short* __restrict__ cth, const float* __restrict__ diagq,
    unsigned short* __restrict__ osh)
{
    __shared__ unsigned short lds[16384 + 2560];
    __shared__ float rmax4[64][4];
    int bx, by; xcd_swz(bx, by);
    const int bh = by, b = bh >> 2, hh = bh & 3;
    const int t0 = bx * 64;
    const int tid = threadIdx.x;
    const int l = tid & 63, w = tid >> 6;
    const int fr = l & 15, fq = l >> 4;

    const int wc1 = w * 64;
    f32x4 a1[4][4];
#pragma unroll
    for (int i = 0; i < 4; ++i)
#pragma unroll
        for (int j = 0; j < 4; ++j) a1[i][j] = (f32x4){0.f, 0.f, 0.f, 0.f};

    const unsigned short* gq = qhi + (size_t)(b * 4096 + t0) * 256 + hh * 64;
#pragma unroll
    for (int ks = 0; ks < 2; ++ks) {
        const int k0 = ks * 32;
        glds16(gq + (size_t)(tid >> 2) * 256 + k0 + (tid & 3) * 8, lds + tid * 8);
#pragma unroll
        for (int i2 = 0; i2 < 4; ++i2) {
            const int c = tid + i2 * 256;
            glds16(pmh + (size_t)(c >> 2) * 64 + k0 + (c & 3) * 8, lds + 2048 + c * 8);
        }
        __syncthreads();
        short8 av[4];
#pragma unroll
        for (int mf = 0; mf < 4; ++mf)
            av[mf] = *(const short8*)&lds[(mf * 16 + fr) * 32 + fq * 8];
#pragma unroll
        for (int nf = 0; nf < 4; ++nf) {
            short8 bh_ = *(const short8*)&lds[2048 + (wc1 + nf * 16 + fr) * 32 + fq * 8];
#pragma unroll
            for (int mf = 0; mf < 4; ++mf)
                a1[mf][nf] = mfma16<true>(av[mf], bh_, a1[mf][nf]);
        }
        __syncthreads();
    }
#pragma unroll
    for (int mf = 0; mf < 4; ++mf)
#pragma unroll
        for (int v = 0; v < 4; ++v) {
            float rm = a1[mf][0][v];
#pragma unroll
            for (int nf = 1; nf < 4; ++nf) rm = fmaxf(rm, a1[mf][nf][v]);
            rm = fmaxf(rm, __shfl_xor(rm, 1));
            rm = fmaxf(rm, __shfl_xor(rm, 2));
            rm = fmaxf(rm, __shfl_xor(rm, 4));
            rm = fmaxf(rm, __shfl_xor(rm, 8));
            if (fr == 0) rmax4[mf * 16 + fq * 4 + v][w] = rm;
        }
    __syncthreads();
#pragma unroll
    for (int mf = 0; mf < 4; ++mf)
#pragma unroll
        for (int v = 0; v < 4; ++v) {
            const int tok = mf * 16 + fq * 4 + v;
            const float dg = diagq[(size_t)(b * 4096 + t0 + tok) * 4 + hh]
                           + fmaxf(fmaxf(rmax4[tok][0], rmax4[tok][1]),
                                   fmaxf(rmax4[tok][2], rmax4[tok][3]));
#pragma unroll
            for (int nf = 0; nf < 4; ++nf) {
                const int m = wc1 + nf * 16 + fr;
                lds[tok * 256 + (m ^ ((tok & 7) << 3))] =
                    fp16rne(RATIO * (__expf(a1[mf][nf][v] - dg) + EPSF));
            }
        }
    __syncthreads();

    unsigned short* lds2 = lds + 16384;
    f32x4 a2[5];
#pragma unroll
    for (int j = 0; j < 5; ++j) a2[j] = (f32x4){0.f, 0.f, 0.f, 0.f};
    const size_t bbase = (size_t)bh * 80 * 256;

    for (int k0 = 0; k0 < 256; k0 += 32) {
        glds16(cth + bbase + (size_t)(tid >> 2) * 256 + k0 + (tid & 3) * 8, lds2 + tid * 8);
        if (tid < 64) {
            const int c = 256 + tid;
            glds16(cth + bbase + (size_t)(c >> 2) * 256 + k0 + (c & 3) * 8, lds2 + c * 8);
        }
        __syncthreads();
        const int tok = w * 16 + fr;
        const int c = ((k0 >> 3) + fq) ^ (tok & 7);
        short8 av = *(const short8*)&lds[tok * 256 + c * 8];
#pragma unroll
        for (int nf = 0; nf < 5; ++nf) {
            short8 bvh = *(const short8*)&lds2[(nf * 16 + fr) * 32 + fq * 8];
            a2[nf] = mfma16<true>(av, bvh, a2[nf]);
        }
        __syncthreads();
    }
#pragma unroll
    for (int v = 0; v < 4; ++v) {
        const float den = __shfl(a2[4][v], (int)(l & 48));
        const float dinv = 1.0f / den;
        const int tok = w * 16 + fq * 4 + v;
        const size_t obase = (size_t)(b * 4096 + t0 + tok) * 256 + hh * 64;
#pragma unroll
        for (int nf = 0; nf < 4; ++nf)
            osh[obase + nf * 16 + fr] = fp16rne(a2[nf][v] * dinv);
    }
}

// ---- pooling + classifier ----
__global__ __launch_bounds__(256) void pool1_kernel(const float* __restrict__ h, float* __restrict__ part)
{
    const int b = blockIdx.x >> 4, ch = blockIdx.x & 15;
    const int tid = threadIdx.x;
    float acc = 0.f;
    for (int n = 0; n < 256; ++n)
        acc += h[((size_t)(b * 4096 + ch * 256 + n)) * 256 + tid];
    part[(size_t)blockIdx.x * 256 + tid] = acc;
}

__global__ __launch_bounds__(256) void pool2_kernel(
    const float* __restrict__ part, const float* __restrict__ cw,
    const float* __restrict__ cb, float* __restrict__ out)
{
    const int b = blockIdx.x, tid = threadIdx.x;
    float acc = 0.f;
#pragma unroll
    for (int c = 0; c < 16; ++c) acc += part[(size_t)(b * 16 + c) * 256 + tid];
    float val = acc * (1.0f / 4096.0f) * cw[tid];
#pragma unroll
    for (int s = 1; s < 64; s <<= 1) val += __shfl_xor(val, s);
    __shared__ float red[4];
    if ((tid & 63) == 0) red[tid >> 6] = val;
    __syncthreads();
    if (tid == 0) out[b] = red[0] + red[1] + red[2] + red[3] + cb[0];
}

extern "C" void kernel_launch(void* const* d_in, const int* in_sizes, int n_in,
                              void* d_out, int out_size, void* d_ws, size_t ws_size,
                              hipStream_t stream)
{
    (void)in_sizes; (void)n_in;
    if (ws_size < WS_BYTES) {
        fill_sentinel<<<1, 64, 0, stream>>>((float*)d_out, out_size);
        return;
    }

    const float* x     = (const float*)d_in[0];
    const float* projw = (const float*)d_in[1];
    const float* projb = (const float*)d_in[2];
    const float* ln1g  = (const float*)d_in[3];
    const float* ln1b  = (const float*)d_in[4];
    const float* wq    = (const float*)d_in[5];
    const float* bq    = (const float*)d_in[6];
    const float* wk    = (const float*)d_in[7];
    const float* bk    = (const float*)d_in[8];
    const float* wv    = (const float*)d_in[9];
    const float* bv    = (const float*)d_in[10];
    const float* wo    = (const float*)d_in[11];
    const float* bo    = (const float*)d_in[12];
    const float* ln2g  = (const float*)d_in[13];
    const float* ln2b  = (const float*)d_in[14];
    const float* w1    = (const float*)d_in[15];
    const float* b1    = (const float*)d_in[16];
    const float* w2    = (const float*)d_in[17];
    const float* b2    = (const float*)d_in[18];
    const float* clfw  = (const float*)d_in[19];
    const float* clfb  = (const float*)d_in[20];
    const float* projm = (const float*)d_in[21];

    char* WS = (char*)d_ws;
    float* h            = (float*)(WS + OFF_H);
    unsigned short* ysh = (unsigned short*)(WS + OFF_YS);
    unsigned short* wts = (unsigned short*)(WS + OFF_WTS);
    unsigned short* khi = (unsigned short*)(WS + OFF_QK);
    unsigned short* qhi = khi + 8388608;
    unsigned short* big = (unsigned short*)(WS + OFF_BIG);   // kpT / ffb / x-split
    unsigned short* vT  = (unsigned short*)(WS + OFF_VT);
    float* ctxp         = (float*)(WS + OFF_CTXP);
    unsigned short* cth = (unsigned short*)(WS + OFF_CTXTH);
    float* diagq        = (float*)(WS + OFF_DIAGQ);
    float* diagk        = (float*)(WS + OFF_DIAGK);
    unsigned* gmax      = (unsigned*)(WS + OFF_GMAX);
    float* pool         = (float*)(WS + OFF_POOL);
    unsigned short* pmt_h = (unsigned short*)(WS + OFF_PMTH);
    unsigned short* pwt_h = (unsigned short*)(WS + OFF_PWTH);
    unsigned short* pwt_l = (unsigned short*)(WS + OFF_PWTL);
    // aliases
    unsigned short* xsh = big;               // prologue only
    unsigned short* xsl = big + 2097152;
    unsigned short* kpT = big;               // [32][256][4096] fp16
    unsigned short* ffb = big;               // [32768][1024] fp16
    unsigned short* osh = ysh;               // o fp16 (ys dead by then)

    // ---- prologue ----
    split_scale<<<8192, 256, 0, stream>>>(x, xsh, xsl, 2097152, 1.0f);
    splitT<<<64, 256, 0, stream>>>(projw, pwt_h, pwt_l, 6, 256);
    tofp16_scale<<<64, 256, 0, stream>>>(projm, pmt_h, 16384, DN);
    vt_init<<<1024, 256, 0, stream>>>(vT, gmax);
    split_weights<<<16384, 256, 0, stream>>>(wq, wk, wv, wo, w1, w2, wts);
    gemm_mf<0, true, true, false><<<dim3(2, 256), 256, 0, stream>>>(xsh, xsl, 64,
        pwt_h, pwt_l, 64, 64, projb, nullptr, h, 256, nullptr, nullptr, nullptr);
    ln_f16<<<8192, 256, 0, stream>>>(h, ln1g, ln1b, ysh);

    for (int l = 0; l < 4; ++l) {
        unsigned short* wl = wts + (size_t)l * 1048576;

        // ---- attention (ysh already holds ln1 output) ----
        gemm_qkv<<<dim3(2, 768), 256, 0, stream>>>(ysh, wl,
            bq + l * 256, bk + l * 256, bv + l * 256, vT, khi, qhi, diagq, diagk);
        gemm_mf<4, false, false, true><<<dim3(2, 1024), 256, 0, stream>>>(khi, nullptr, 64,
            pmt_h, nullptr, 64, 64, nullptr, nullptr, nullptr, 256, nullptr, nullptr, gmax + l);
        gemm_mf<6, false, false, true><<<dim3(2, 1024), 256, 0, stream>>>(khi, nullptr, 64,
            pmt_h, nullptr, 64, 64, nullptr, nullptr, nullptr, 256, kpT, diagk, gmax + l);
        ctx_mfma<<<dim3(16, 32), 256, 0, stream>>>(kpT, vT, ctxp);
        ctx_fix<<<dim3(4, 32), 256, 0, stream>>>(ctxp, cth);
        qo_mfma<<<dim3(64, 32), 256, 0, stream>>>(qhi, pmt_h, cth, diagq, osh);
        // wo + residual + ln2 fused (reads osh rows, writes h + ysh same rows: safe)
        gemm_w_ln<<<256, 512, 0, stream>>>(osh, 256, 256, wl + WOF,
            bo + l * 256, h, ln2g + l * 256, ln2b + l * 256, ysh);

        // ---- feed-forward ----
        gemm_glu<<<dim3(16, 256), 256, 0, stream>>>(ysh, wl + W1F,
            b1 + (size_t)l * 2048, ffb);
        // w2 + residual + ln1[l+1] fused (last layer: LN output unused, params harmless)
        const float* ng = (l < 3) ? (ln1g + (l + 1) * 256) : ln1g;
        const float* nb = (l < 3) ? (ln1b + (l + 1) * 256) : ln1b;
        gemm_w_ln<<<256, 512, 0, stream>>>(ffb, 1024, 1024, wl + W2F,
            b2 + l * 256, h, ng, nb, ysh);
    }

    pool1_kernel<<<128, 256, 0, stream>>>(h, pool);
    pool2_kernel<<<8, 256, 0, stream>>>(pool, clfw, clfb, (float*)d_out);
}